// Round 3
// baseline (399.513 us; speedup 1.0000x reference)
//
#include <hip/hip_runtime.h>

// ---------------- problem constants ----------------
#define BB 2
#define KFR 8          // frames
#define NQ 3072        // 3*32*32 triplane queries
#define NPIX 256
#define NKV 2048       // KFR*NPIX
#define NH 8
#define HD 16

// ---------------- workspace layout (float offsets) ----------------
#define OFF_TK      0u         // 128*512   wk@k_w
#define OFF_TV      65536u     // 128*512   wv@v_w
#define OFF_WQ      131072u    // 128*64    wq@q_w
#define OFF_WO      139264u    // 64*128    out_w@attn_out_w
#define OFF_BK1     147456u    // 128       wk@k_b + wk_b
#define OFF_BV1     147584u    // 128
#define OFF_BO      147712u    // 64        out_w@attn_out_b + out_b
#define OFF_WKF     147776u    // 128*1280  Tk@conv_w
#define OFF_WVF     311616u    // 128*1280
#define OFF_BKF     475456u    // 128       Tk@conv_b + bk1
#define OFF_BVF     475584u    // 128
#define OFF_MB      475712u    // B*8*3072*8 u32 visibility mask bits
#define OFF_QH      868928u    // B*3072*128 (scale folded)
#define OFF_KVP     1655360u   // 4(chq)*B*2048*256 partial K|V
#define OFF_KH      5849664u   // B*2048*128
#define OFF_VH      6373952u   // B*2048*128
#define OFF_PART    6898240u   // 16bh*8f*17slot*3072q partial sums
#define OFF_ATTN    13582912u  // B*3072*128

// ============ small fused-weight products (all K=128 dots) ============
__global__ __launch_bounds__(256) void k_fuse1(
    const float* __restrict__ wk, const float* __restrict__ k_w,
    const float* __restrict__ wv, const float* __restrict__ v_w,
    const float* __restrict__ wq, const float* __restrict__ q_w,
    const float* __restrict__ out_w, const float* __restrict__ aow,
    const float* __restrict__ k_b, const float* __restrict__ wk_b,
    const float* __restrict__ v_b, const float* __restrict__ wv_b,
    const float* __restrict__ aob, const float* __restrict__ out_b,
    float* __restrict__ ws) {
  int idx = blockIdx.x * 256 + threadIdx.x;
  if (idx < 131072) {                 // Tk / Tv : [o<128][m<512]
    const float* Wb = (idx < 65536) ? wk : wv;
    const float* Ws = (idx < 65536) ? k_w : v_w;
    float* dst = ws + ((idx < 65536) ? OFF_TK : OFF_TV);
    int t = idx & 65535; int o = t >> 9, m = t & 511;
    float s = 0.f;
#pragma unroll 8
    for (int j = 0; j < 128; ++j) s = fmaf(Wb[o*128+j], Ws[j*512+m], s);
    dst[t] = s;
  } else if (idx < 139264) {          // Wq : [o<128][c<64]
    int t = idx - 131072; int o = t >> 6, c = t & 63;
    float s = 0.f;
#pragma unroll 8
    for (int j = 0; j < 128; ++j) s = fmaf(wq[o*128+j], q_w[j*64+c], s);
    ws[OFF_WQ + t] = s;
  } else if (idx < 147456) {          // Wo : [c<64][o<128]
    int t = idx - 139264; int c = t >> 7, o = t & 127;
    float s = 0.f;
#pragma unroll 8
    for (int j = 0; j < 128; ++j) s = fmaf(out_w[c*128+j], aow[j*128+o], s);
    ws[OFF_WO + t] = s;
  } else if (idx < 147712) {          // bk1 / bv1
    int t = idx - 147456; int o = t & 127;
    const float* Wb = (t < 128) ? wk : wv;
    const float* bi = (t < 128) ? k_b : v_b;
    const float* ba = (t < 128) ? wk_b : wv_b;
    float s = 0.f;
    for (int j = 0; j < 128; ++j) s = fmaf(Wb[o*128+j], bi[j], s);
    ws[(t < 128 ? OFF_BK1 : OFF_BV1) + o] = s + ba[o];
  } else if (idx < 147776) {          // bo
    int c = idx - 147712;
    float s = 0.f;
    for (int j = 0; j < 128; ++j) s = fmaf(out_w[c*128+j], aob[j], s);
    ws[OFF_BO + c] = s + out_b[c];
  }
}

// ============ Wk_full/Wv_full = T @ conv_w  (128x1280, K=512) ============
__global__ __launch_bounds__(256) void k_fuse2(
    const float* __restrict__ Tk, const float* __restrict__ Tv,
    const float* __restrict__ conv_w, float* __restrict__ Wkf, float* __restrict__ Wvf) {
  __shared__ float Ts[8][512];
  int tid = threadIdx.x;
  const float* T = blockIdx.z ? Tv : Tk;
  float* W = blockIdx.z ? Wvf : Wkf;
  int r0 = blockIdx.y * 8;
  for (int i = tid; i < 4096; i += 256) Ts[i >> 9][i & 511] = T[(r0 + (i >> 9))*512 + (i & 511)];
  __syncthreads();
  int c = blockIdx.x * 256 + tid;
  float acc[8] = {0,0,0,0,0,0,0,0};
  for (int m = 0; m < 512; ++m) {
    float w = conv_w[(size_t)m*1280 + c];
#pragma unroll
    for (int r = 0; r < 8; ++r) acc[r] = fmaf(Ts[r][m], w, acc[r]);
  }
#pragma unroll
  for (int r = 0; r < 8; ++r) W[(size_t)(r0 + r)*1280 + c] = acc[r];
}

// ============ fused biases through conv ============
__global__ __launch_bounds__(256) void k_biasf(
    const float* __restrict__ Tk, const float* __restrict__ Tv,
    const float* __restrict__ conv_b, const float* __restrict__ bk1,
    const float* __restrict__ bv1, float* __restrict__ bkf, float* __restrict__ bvf) {
  int tid = threadIdx.x;
  const float* T = (tid < 128) ? Tk : Tv;
  int o = tid & 127;
  float s = 0.f;
  for (int m = 0; m < 512; ++m) s = fmaf(T[o*512+m], conv_b[m], s);
  if (tid < 128) bkf[o] = s + bk1[o]; else bvf[o] = s + bv1[o];
}

// ============ visibility mask bits per (b,frame,q): 8 x u32 ============
// NOTE: uses sqrtf(d2) < 2.0f to match the reference's `sqrt(sum) < SIGMA`
// bit-exactly on borderline values (monotonic but rounding can flip d2<4).
__global__ __launch_bounds__(256) void k_maskbits(
    const float* __restrict__ proj, const float* __restrict__ vfr,
    unsigned* __restrict__ MB) {
  int idx = blockIdx.x * 256 + threadIdx.x;   // (b*8+f)*NQ + q ; total 49152
  int q = idx % NQ; int bk = idx / NQ;
  int plane = q >> 10, rem = q & 1023;
  float fi = (float)(rem >> 5), fj = (float)(rem & 31);
  float cx, cy, cz;
  if (plane == 0)      { cx = fj;    cy = 15.5f; cz = fi; }
  else if (plane == 1) { cx = fj;    cy = fi;    cz = 15.5f; }
  else                 { cx = 15.5f; cy = fj;    cz = fi; }
  cx = ((cx / 31.0f) - 0.5f) * 2.0f * 1.10001f;
  cy = ((cy / 31.0f) - 0.5f) * 2.0f * 1.10001f;
  cz = ((cz / 31.0f) - 0.5f) * 2.0f * 1.10001f;
  const float* P = proj + bk * 16;
  float c0 = cx*P[0] + cy*P[1] + cz*P[2] + P[3];
  float c1 = cx*P[4] + cy*P[5] + cz*P[6] + P[7];
  float c2 = cx*P[8] + cy*P[9] + cz*P[10] + P[11];
  float x = (c0 / c2) / 223.0f * 15.0f;
  float y = (c1 / c2) / 223.0f * 15.0f;
  bool invalid = (1.0f - vfr[bk]) > 0.0f;
  unsigned out[8];
#pragma unroll
  for (int w = 0; w < 8; ++w) {
    unsigned word = 0;
#pragma unroll
    for (int i = 0; i < 32; ++i) {
      int p = w*32 + i;
      float dx = x - (float)(p & 15);
      float dy = y - (float)(p >> 4);
      float d2 = fmaf(dx, dx, dy*dy);
      word |= (sqrtf(d2) < 2.0f ? 1u : 0u) << i;
    }
    out[w] = invalid ? 0xFFFFFFFFu : word;
  }
  uint4* dst = (uint4*)(MB + (size_t)idx * 8);
  dst[0] = make_uint4(out[0], out[1], out[2], out[3]);
  dst[1] = make_uint4(out[4], out[5], out[6], out[7]);
}

// ============ QH = tq @ Wq^T + wq_b, scaled by 0.25 ============
__global__ __launch_bounds__(256) void k_qh(
    const float* __restrict__ tf, const float* __restrict__ Wq,
    const float* __restrict__ wq_b, float* __restrict__ QH) {
  __shared__ float A[64][65];    // [c][q]
  __shared__ float W[128][65];   // [o][c]
  int b = blockIdx.y, q0 = blockIdx.x * 64, tid = threadIdx.x;
  for (int i = tid; i < 4096; i += 256) A[i >> 6][i & 63] = tf[((size_t)(b*64) + (i >> 6))*NQ + q0 + (i & 63)];
  for (int i = tid; i < 8192; i += 256) W[i >> 6][i & 63] = Wq[i];
  __syncthreads();
  int og = tid & 15, qg = tid >> 4;   // o = og*8+jo ; q = q0+qg*4+jq
  float acc[4][8] = {};
  for (int c = 0; c < 64; ++c) {
    float a[4];
#pragma unroll
    for (int jq = 0; jq < 4; ++jq) a[jq] = A[c][qg*4 + jq];
#pragma unroll
    for (int jo = 0; jo < 8; ++jo) {
      float w = W[og*8 + jo][c];
#pragma unroll
      for (int jq = 0; jq < 4; ++jq) acc[jq][jo] = fmaf(a[jq], w, acc[jq][jo]);
    }
  }
#pragma unroll
  for (int jq = 0; jq < 4; ++jq) {
    float* dst = QH + ((size_t)(b*NQ) + q0 + qg*4 + jq)*128 + og*8;
#pragma unroll
    for (int jo = 0; jo < 8; ++jo) dst[jo] = (acc[jq][jo] + wq_b[og*8 + jo]) * 0.25f;
  }
}

// ============ KV projection: partial over a quarter of the 1280 channels ============
__global__ __launch_bounds__(256) void k_kvh(
    const float* __restrict__ X, const float* __restrict__ Wk,
    const float* __restrict__ Wv, float* __restrict__ KVP) {
  __shared__ float A[16][33];     // [c-sub][t] pad
  __shared__ float Ws[256][17];   // [o (K|V)][c-sub] pad
  int tid = threadIdx.x;
  int t0 = blockIdx.x * 32;
  int ch = blockIdx.y;            // 0..3
  int b  = blockIdx.z;
  int c_base = ch * 320;
  int tg = tid >> 5;   // t = t0 + tg + 8*jt
  int og = tid & 31;   // o = og + 32*jo
  float acc[4][8] = {};
  const float* Xb = X + (size_t)b * 1280 * NKV;
  for (int ct = 0; ct < 20; ++ct) {
    int c0 = c_base + ct * 16;
    __syncthreads();
#pragma unroll
    for (int r = 0; r < 2; ++r) {
      int ii = tid + r * 256;
      A[ii >> 5][ii & 31] = Xb[(size_t)(c0 + (ii >> 5))*NKV + t0 + (ii & 31)];
    }
#pragma unroll
    for (int r = 0; r < 16; ++r) {
      int ii = tid + r * 256;
      int o = ii >> 4, cc = ii & 15;
      Ws[o][cc] = (o < 128) ? Wk[(size_t)o*1280 + c0 + cc] : Wv[(size_t)(o-128)*1280 + c0 + cc];
    }
    __syncthreads();
#pragma unroll
    for (int cc = 0; cc < 16; ++cc) {
      float a[4], w[8];
#pragma unroll
      for (int jt = 0; jt < 4; ++jt) a[jt] = A[cc][tg + 8*jt];
#pragma unroll
      for (int jo = 0; jo < 8; ++jo) w[jo] = Ws[og + 32*jo][cc];
#pragma unroll
      for (int jt = 0; jt < 4; ++jt)
#pragma unroll
        for (int jo = 0; jo < 8; ++jo) acc[jt][jo] = fmaf(a[jt], w[jo], acc[jt][jo]);
    }
  }
  float* dst = KVP + (size_t)(ch*2 + b) * NKV * 256;
#pragma unroll
  for (int jt = 0; jt < 4; ++jt)
#pragma unroll
    for (int jo = 0; jo < 8; ++jo)
      dst[(size_t)(t0 + tg + 8*jt)*256 + og + 32*jo] = acc[jt][jo];
}

// ============ combine KV partials + bias -> KH, VH ============
__global__ __launch_bounds__(256) void k_kvcomb(
    const float* __restrict__ KVP, const float* __restrict__ bkf,
    const float* __restrict__ bvf, float* __restrict__ KH, float* __restrict__ VH) {
  int idx = blockIdx.x * 256 + threadIdx.x;   // 2*2048*256
  int o = idx & 255; int bt = idx >> 8;       // b*2048 + t
  int b = bt >> 11, t = bt & 2047;
  float v = 0.f;
#pragma unroll
  for (int ch = 0; ch < 4; ++ch)
    v += KVP[((size_t)(ch*2 + b) * NKV + t)*256 + o];
  if (o < 128) KH[(size_t)bt*128 + o]        = v + bkf[o];
  else         VH[(size_t)bt*128 + (o-128)]  = v + bvf[o-128];
}

// ============ attention: frame-split(8), 2 q-rows/thread, bitmask, plain exp-sum ============
__global__ __launch_bounds__(256, 3) void k_attn(
    const float* __restrict__ QH, const float* __restrict__ KH,
    const float* __restrict__ VH, const unsigned* __restrict__ MB,
    float* __restrict__ PART) {
  __shared__ float Ks[256][16];
  __shared__ float Vs[256][16];
  int bh = blockIdx.z, b = bh >> 3, h = bh & 7;
  int frame = blockIdx.y;
  int tid = threadIdx.x;
  int qA = blockIdx.x * 512 + tid;           // qB = qA + 256
  // stage K/V tiles for this frame
  {
    const float4* Kp = (const float4*)(KH + ((size_t)(b*NKV + frame*NPIX))*128 + h*16);
    const float4* Vp = (const float4*)(VH + ((size_t)(b*NKV + frame*NPIX))*128 + h*16);
#pragma unroll
    for (int j = 0; j < 4; ++j) {
      int f = tid + j * 256;
      int p = f >> 2, dq = f & 3;
      ((float4*)&Ks[p][0])[dq] = Kp[p*32 + dq];
      ((float4*)&Vs[p][0])[dq] = Vp[p*32 + dq];
    }
  }
  // Q rows in registers
  float qa[16], qb[16];
  {
    const float4* QpA = (const float4*)(QH + ((size_t)(b*NQ) + qA)*128 + h*16);
    const float4* QpB = (const float4*)(QH + ((size_t)(b*NQ) + qA + 256)*128 + h*16);
#pragma unroll
    for (int i = 0; i < 4; ++i) {
      float4 ta = QpA[i], tb = QpB[i];
      qa[4*i+0] = ta.x; qa[4*i+1] = ta.y; qa[4*i+2] = ta.z; qa[4*i+3] = ta.w;
      qb[4*i+0] = tb.x; qb[4*i+1] = tb.y; qb[4*i+2] = tb.z; qb[4*i+3] = tb.w;
    }
  }
  // mask words
  unsigned mwA[8], mwB[8];
  {
    const unsigned* MBb = MB + (size_t)(b*8 + frame) * NQ * 8;
    uint4 a0 = ((const uint4*)(MBb + (size_t)qA*8))[0];
    uint4 a1 = ((const uint4*)(MBb + (size_t)qA*8))[1];
    uint4 b0 = ((const uint4*)(MBb + (size_t)(qA+256)*8))[0];
    uint4 b1 = ((const uint4*)(MBb + (size_t)(qA+256)*8))[1];
    mwA[0]=a0.x; mwA[1]=a0.y; mwA[2]=a0.z; mwA[3]=a0.w;
    mwA[4]=a1.x; mwA[5]=a1.y; mwA[6]=a1.z; mwA[7]=a1.w;
    mwB[0]=b0.x; mwB[1]=b0.y; mwB[2]=b0.z; mwB[3]=b0.w;
    mwB[4]=b1.x; mwB[5]=b1.y; mwB[6]=b1.z; mwB[7]=b1.w;
  }
  __syncthreads();
  float lA = 0.f, lB = 0.f;
  float accA[16] = {}, accB[16] = {};
#pragma unroll 1
  for (int w = 0; w < 8; ++w) {
    unsigned bitsA = mwA[w], bitsB = mwB[w];
#pragma unroll
    for (int i = 0; i < 32; ++i) {
      int p = (w << 5) | i;
      float4 k0 = ((float4*)&Ks[p][0])[0];
      float4 k1 = ((float4*)&Ks[p][0])[1];
      float4 k2 = ((float4*)&Ks[p][0])[2];
      float4 k3 = ((float4*)&Ks[p][0])[3];
      float sA = fmaf(k0.x, qa[0], fmaf(k0.y, qa[1], fmaf(k0.z, qa[2], k0.w*qa[3])));
      sA = fmaf(k1.x, qa[4], fmaf(k1.y, qa[5], fmaf(k1.z, qa[6], fmaf(k1.w, qa[7], sA))));
      sA = fmaf(k2.x, qa[8], fmaf(k2.y, qa[9], fmaf(k2.z, qa[10], fmaf(k2.w, qa[11], sA))));
      sA = fmaf(k3.x, qa[12], fmaf(k3.y, qa[13], fmaf(k3.z, qa[14], fmaf(k3.w, qa[15], sA))));
      float sB = fmaf(k0.x, qb[0], fmaf(k0.y, qb[1], fmaf(k0.z, qb[2], k0.w*qb[3])));
      sB = fmaf(k1.x, qb[4], fmaf(k1.y, qb[5], fmaf(k1.z, qb[6], fmaf(k1.w, qb[7], sB))));
      sB = fmaf(k2.x, qb[8], fmaf(k2.y, qb[9], fmaf(k2.z, qb[10], fmaf(k2.w, qb[11], sB))));
      sB = fmaf(k3.x, qb[12], fmaf(k3.y, qb[13], fmaf(k3.z, qb[14], fmaf(k3.w, qb[15], sB))));
      sA = (bitsA & (1u << i)) ? -1e30f : sA;
      sB = (bitsB & (1u << i)) ? -1e30f : sB;
      float pA = __expf(sA), pB = __expf(sB);
      lA += pA; lB += pB;
      float4 v0 = ((float4*)&Vs[p][0])[0];
      float4 v1 = ((float4*)&Vs[p][0])[1];
      float4 v2 = ((float4*)&Vs[p][0])[2];
      float4 v3 = ((float4*)&Vs[p][0])[3];
      accA[0]  = fmaf(pA, v0.x, accA[0]);  accA[1]  = fmaf(pA, v0.y, accA[1]);
      accA[2]  = fmaf(pA, v0.z, accA[2]);  accA[3]  = fmaf(pA, v0.w, accA[3]);
      accA[4]  = fmaf(pA, v1.x, accA[4]);  accA[5]  = fmaf(pA, v1.y, accA[5]);
      accA[6]  = fmaf(pA, v1.z, accA[6]);  accA[7]  = fmaf(pA, v1.w, accA[7]);
      accA[8]  = fmaf(pA, v2.x, accA[8]);  accA[9]  = fmaf(pA, v2.y, accA[9]);
      accA[10] = fmaf(pA, v2.z, accA[10]); accA[11] = fmaf(pA, v2.w, accA[11]);
      accA[12] = fmaf(pA, v3.x, accA[12]); accA[13] = fmaf(pA, v3.y, accA[13]);
      accA[14] = fmaf(pA, v3.z, accA[14]); accA[15] = fmaf(pA, v3.w, accA[15]);
      accB[0]  = fmaf(pB, v0.x, accB[0]);  accB[1]  = fmaf(pB, v0.y, accB[1]);
      accB[2]  = fmaf(pB, v0.z, accB[2]);  accB[3]  = fmaf(pB, v0.w, accB[3]);
      accB[4]  = fmaf(pB, v1.x, accB[4]);  accB[5]  = fmaf(pB, v1.y, accB[5]);
      accB[6]  = fmaf(pB, v1.z, accB[6]);  accB[7]  = fmaf(pB, v1.w, accB[7]);
      accB[8]  = fmaf(pB, v2.x, accB[8]);  accB[9]  = fmaf(pB, v2.y, accB[9]);
      accB[10] = fmaf(pB, v2.z, accB[10]); accB[11] = fmaf(pB, v2.w, accB[11]);
      accB[12] = fmaf(pB, v3.x, accB[12]); accB[13] = fmaf(pB, v3.y, accB[13]);
      accB[14] = fmaf(pB, v3.z, accB[14]); accB[15] = fmaf(pB, v3.w, accB[15]);
    }
  }
  // partial sums, layout [bh][frame][slot(17)][q] fully coalesced
  float* base = PART + (size_t)(bh*8 + frame) * 17 * NQ;
  base[qA] = lA; base[qA + 256] = lB;
#pragma unroll
  for (int d = 0; d < 16; ++d) {
    base[(size_t)(1 + d)*NQ + qA]       = accA[d];
    base[(size_t)(1 + d)*NQ + qA + 256] = accB[d];
  }
}

// ============ combine frame partials -> ATTN ============
__global__ __launch_bounds__(256) void k_attncomb(
    const float* __restrict__ PART, float* __restrict__ ATTN) {
  int idx = blockIdx.x * 256 + threadIdx.x;   // 16*3072
  int bh = idx / NQ; int q = idx % NQ;
  int b = bh >> 3, h = bh & 7;
  const float* Pb = PART + (size_t)(bh*8) * 17 * NQ + q;
  float l = 0.f; float acc[16] = {};
#pragma unroll 1
  for (int f = 0; f < 8; ++f) {
    const float* Pf = Pb + (size_t)f * 17 * NQ;
    l += Pf[0];
#pragma unroll
    for (int d = 0; d < 16; ++d) acc[d] += Pf[(size_t)(1 + d)*NQ];
  }
  float inv = 1.0f / l;
  float* O = ATTN + ((size_t)(b*NQ + q))*128 + h*16;
#pragma unroll
  for (int d = 0; d < 16; ++d) O[d] = acc[d] * inv;
}

// ============ out = ATTN @ Wo^T + bo, stored (b, c, n) ============
__global__ __launch_bounds__(256) void k_out(
    const float* __restrict__ ATTN, const float* __restrict__ Wo,
    const float* __restrict__ bo, float* __restrict__ out) {
  __shared__ float A[64][129];
  __shared__ float W[64][129];
  int b = blockIdx.y, n0 = blockIdx.x * 64, tid = threadIdx.x;
  for (int i = tid; i < 8192; i += 256) { int n = i >> 7, o = i & 127; A[n][o] = ATTN[((size_t)(b*NQ) + n0 + n)*128 + o]; }
  for (int i = tid; i < 8192; i += 256) { int c = i >> 7, o = i & 127; W[c][o] = Wo[i]; }
  __syncthreads();
  int ng = tid & 31, cg = tid >> 5;   // n = ng, ng+32 ; c = cg*8+jc
  float acc[2][8] = {};
  for (int o = 0; o < 128; ++o) {
    float a0 = A[ng][o], a1 = A[ng + 32][o];
#pragma unroll
    for (int jc = 0; jc < 8; ++jc) {
      float w = W[cg*8 + jc][o];
      acc[0][jc] = fmaf(a0, w, acc[0][jc]);
      acc[1][jc] = fmaf(a1, w, acc[1][jc]);
    }
  }
#pragma unroll
  for (int jn = 0; jn < 2; ++jn)
#pragma unroll
    for (int jc = 0; jc < 8; ++jc) {
      int c = cg*8 + jc;
      out[((size_t)(b*64) + c)*NQ + n0 + ng + 32*jn] = acc[jn][jc] + bo[c];
    }
}

extern "C" void kernel_launch(void* const* d_in, const int* in_sizes, int n_in,
                              void* d_out, int out_size, void* d_ws, size_t ws_size,
                              hipStream_t stream) {
  const float* tf     = (const float*)d_in[0];
  const float* imf    = (const float*)d_in[1];
  const float* proj   = (const float*)d_in[2];
  const float* vfr    = (const float*)d_in[3];
  const float* conv_w = (const float*)d_in[4];
  const float* conv_b = (const float*)d_in[5];
  const float* q_w    = (const float*)d_in[6];
  const float* k_w    = (const float*)d_in[7];
  const float* k_b    = (const float*)d_in[8];
  const float* v_w    = (const float*)d_in[9];
  const float* v_b    = (const float*)d_in[10];
  const float* wq     = (const float*)d_in[11];
  const float* wq_b   = (const float*)d_in[12];
  const float* wk     = (const float*)d_in[13];
  const float* wk_b   = (const float*)d_in[14];
  const float* wv     = (const float*)d_in[15];
  const float* wv_b   = (const float*)d_in[16];
  const float* aow    = (const float*)d_in[17];
  const float* aob    = (const float*)d_in[18];
  const float* out_w  = (const float*)d_in[19];
  const float* out_b  = (const float*)d_in[20];
  float* ws  = (float*)d_ws;
  float* out = (float*)d_out;

  k_fuse1<<<dim3(578), dim3(256), 0, stream>>>(wk, k_w, wv, v_w, wq, q_w, out_w, aow,
                                               k_b, wk_b, v_b, wv_b, aob, out_b, ws);
  k_fuse2<<<dim3(5,16,2), dim3(256), 0, stream>>>(ws+OFF_TK, ws+OFF_TV, conv_w, ws+OFF_WKF, ws+OFF_WVF);
  k_biasf<<<dim3(1), dim3(256), 0, stream>>>(ws+OFF_TK, ws+OFF_TV, conv_b, ws+OFF_BK1, ws+OFF_BV1,
                                             ws+OFF_BKF, ws+OFF_BVF);
  k_maskbits<<<dim3(192), dim3(256), 0, stream>>>(proj, vfr, (unsigned*)(ws+OFF_MB));
  k_qh<<<dim3(48,2), dim3(256), 0, stream>>>(tf, ws+OFF_WQ, wq_b, ws+OFF_QH);
  k_kvh<<<dim3(64,4,2), dim3(256), 0, stream>>>(imf, ws+OFF_WKF, ws+OFF_WVF, ws+OFF_KVP);
  k_kvcomb<<<dim3(4096), dim3(256), 0, stream>>>(ws+OFF_KVP, ws+OFF_BKF, ws+OFF_BVF, ws+OFF_KH, ws+OFF_VH);
  k_attn<<<dim3(6,8,16), dim3(256), 0, stream>>>(ws+OFF_QH, ws+OFF_KH, ws+OFF_VH,
                                                 (const unsigned*)(ws+OFF_MB), ws+OFF_PART);
  k_attncomb<<<dim3(192), dim3(256), 0, stream>>>(ws+OFF_PART, ws+OFF_ATTN);
  k_out<<<dim3(48,2), dim3(256), 0, stream>>>(ws+OFF_ATTN, ws+OFF_WO, ws+OFF_BO, out);
}

// Round 6
// 286.703 us; speedup vs baseline: 1.3935x; 1.3935x over previous
//
#include <hip/hip_runtime.h>

// ---------------- problem constants ----------------
#define NQ 3072        // 3*32*32 triplane queries
#define NPIX 256
#define NKV 2048
#define NH 8

typedef __attribute__((ext_vector_type(8))) short short8;
typedef __attribute__((ext_vector_type(16))) float f32x16;

union Frag {
  int4 i;
  short8 s;
  unsigned u[4];
  unsigned short h[8];
};

__device__ inline unsigned short f2bf(float x) {
  unsigned u = __float_as_uint(x);
  return (unsigned short)((u + 0x7FFFu + ((u >> 16) & 1u)) >> 16);
}
__device__ inline unsigned f2bf2(float lo, float hi) {
  unsigned r;
  asm("v_cvt_pk_bf16_f32 %0, %1, %2" : "=v"(r) : "v"(lo), "v"(hi));
  return r;
}
__device__ inline void plswap(unsigned& a, unsigned& b) {
  asm("v_permlane32_swap_b32 %0, %1" : "+v"(a), "+v"(b));
}

// ---------------- workspace layout (float offsets) ----------------
#define OFF_TK      0u         // 128*512 fp32   wk@k_w
#define OFF_TV      65536u     // 128*512 fp32   wv@v_w
#define OFF_WQ      131072u    // 128*64 fp32    wq@q_w
#define OFF_WO      139264u    // 64*128 fp32    out_w@attn_out_w
#define OFF_BK1     147456u    // 128
#define OFF_BV1     147584u    // 128
#define OFF_BO      147712u    // 64
#define OFF_WB      147776u    // bf16 256*1280  fused conv->K|V weight
#define OFF_BKF     311616u    // 128 fp32
#define OFF_BVF     311744u    // 128 fp32
#define OFF_MB      311872u    // u32 2*8*3072*8 visibility bits
#define OFF_QB      705088u    // bf16 2*3072*128 (scale folded)
#define OFF_KVP     1098304u   // fp32 4ch*2b*2048*256 partials
#define OFF_KB      5292608u   // bf16 2*2048*128
#define OFF_VB      5554752u   // bf16 2*2048*128
#define OFF_VT      5816896u   // bf16 2b*8f*8h*32*256 V^T augmented (row16=1)
#define OFF_ATTN    6341184u   // fp32 2*3072*128

// ============ small fused-weight products (all K=128 dots) ============
__global__ __launch_bounds__(256) void k_fuse1(
    const float* __restrict__ wk, const float* __restrict__ k_w,
    const float* __restrict__ wv, const float* __restrict__ v_w,
    const float* __restrict__ wq, const float* __restrict__ q_w,
    const float* __restrict__ out_w, const float* __restrict__ aow,
    const float* __restrict__ k_b, const float* __restrict__ wk_b,
    const float* __restrict__ v_b, const float* __restrict__ wv_b,
    const float* __restrict__ aob, const float* __restrict__ out_b,
    float* __restrict__ ws) {
  int idx = blockIdx.x * 256 + threadIdx.x;
  if (idx < 131072) {                 // Tk / Tv : [o<128][m<512]
    const float* Wb = (idx < 65536) ? wk : wv;
    const float* Ws = (idx < 65536) ? k_w : v_w;
    float* dst = ws + ((idx < 65536) ? OFF_TK : OFF_TV);
    int t = idx & 65535; int o = t >> 9, m = t & 511;
    float s = 0.f;
#pragma unroll 8
    for (int j = 0; j < 128; ++j) s = fmaf(Wb[o*128+j], Ws[j*512+m], s);
    dst[t] = s;
  } else if (idx < 139264) {          // Wq : [o<128][c<64]
    int t = idx - 131072; int o = t >> 6, c = t & 63;
    float s = 0.f;
#pragma unroll 8
    for (int j = 0; j < 128; ++j) s = fmaf(wq[o*128+j], q_w[j*64+c], s);
    ws[OFF_WQ + t] = s;
  } else if (idx < 147456) {          // Wo : [c<64][o<128]
    int t = idx - 139264; int c = t >> 7, o = t & 127;
    float s = 0.f;
#pragma unroll 8
    for (int j = 0; j < 128; ++j) s = fmaf(out_w[c*128+j], aow[j*128+o], s);
    ws[OFF_WO + t] = s;
  } else if (idx < 147712) {          // bk1 / bv1
    int t = idx - 147456; int o = t & 127;
    const float* Wb = (t < 128) ? wk : wv;
    const float* bi = (t < 128) ? k_b : v_b;
    const float* ba = (t < 128) ? wk_b : wv_b;
    float s = 0.f;
    for (int j = 0; j < 128; ++j) s = fmaf(Wb[o*128+j], bi[j], s);
    ws[(t < 128 ? OFF_BK1 : OFF_BV1) + o] = s + ba[o];
  } else if (idx < 147776) {          // bo
    int c = idx - 147712;
    float s = 0.f;
    for (int j = 0; j < 128; ++j) s = fmaf(out_w[c*128+j], aob[j], s);
    ws[OFF_BO + c] = s + out_b[c];
  }
}

// ============ WB = [Tk;Tv] @ conv_w  -> bf16 (256x1280, K=512) ============
__global__ __launch_bounds__(256) void k_fuse2(
    const float* __restrict__ Tk, const float* __restrict__ Tv,
    const float* __restrict__ conv_w, unsigned short* __restrict__ WB) {
  __shared__ float Ts[8][512];
  int tid = threadIdx.x;
  const float* T = blockIdx.z ? Tv : Tk;
  int r0 = blockIdx.y * 8;
  for (int i = tid; i < 4096; i += 256) Ts[i >> 9][i & 511] = T[(r0 + (i >> 9))*512 + (i & 511)];
  __syncthreads();
  int c = blockIdx.x * 256 + tid;
  float acc[8] = {0,0,0,0,0,0,0,0};
  for (int m = 0; m < 512; ++m) {
    float w = conv_w[(size_t)m*1280 + c];
#pragma unroll
    for (int r = 0; r < 8; ++r) acc[r] = fmaf(Ts[r][m], w, acc[r]);
  }
#pragma unroll
  for (int r = 0; r < 8; ++r)
    WB[(size_t)(blockIdx.z*128 + r0 + r)*1280 + c] = f2bf(acc[r]);
}

// ============ fused biases through conv ============
__global__ __launch_bounds__(256) void k_biasf(
    const float* __restrict__ Tk, const float* __restrict__ Tv,
    const float* __restrict__ conv_b, const float* __restrict__ bk1,
    const float* __restrict__ bv1, float* __restrict__ bkf, float* __restrict__ bvf) {
  int tid = threadIdx.x;
  const float* T = (tid < 128) ? Tk : Tv;
  int o = tid & 127;
  float s = 0.f;
  for (int m = 0; m < 512; ++m) s = fmaf(T[o*512+m], conv_b[m], s);
  if (tid < 128) bkf[o] = s + bk1[o]; else bvf[o] = s + bv1[o];
}

// ============ visibility mask bits per (b,frame,q): 8 x u32 ============
__global__ __launch_bounds__(256) void k_maskbits(
    const float* __restrict__ proj, const float* __restrict__ vfr,
    unsigned* __restrict__ MB) {
  int idx = blockIdx.x * 256 + threadIdx.x;   // (b*8+f)*NQ + q
  int q = idx % NQ; int bk = idx / NQ;
  int plane = q >> 10, rem = q & 1023;
  float fi = (float)(rem >> 5), fj = (float)(rem & 31);
  float cx, cy, cz;
  if (plane == 0)      { cx = fj;    cy = 15.5f; cz = fi; }
  else if (plane == 1) { cx = fj;    cy = fi;    cz = 15.5f; }
  else                 { cx = 15.5f; cy = fj;    cz = fi; }
  cx = ((cx / 31.0f) - 0.5f) * 2.0f * 1.10001f;
  cy = ((cy / 31.0f) - 0.5f) * 2.0f * 1.10001f;
  cz = ((cz / 31.0f) - 0.5f) * 2.0f * 1.10001f;
  const float* P = proj + bk * 16;
  float c0 = cx*P[0] + cy*P[1] + cz*P[2] + P[3];
  float c1 = cx*P[4] + cy*P[5] + cz*P[6] + P[7];
  float c2 = cx*P[8] + cy*P[9] + cz*P[10] + P[11];
  float x = (c0 / c2) / 223.0f * 15.0f;
  float y = (c1 / c2) / 223.0f * 15.0f;
  bool invalid = (1.0f - vfr[bk]) > 0.0f;
  unsigned out[8];
#pragma unroll
  for (int w = 0; w < 8; ++w) {
    unsigned word = 0;
#pragma unroll
    for (int i = 0; i < 32; ++i) {
      int p = w*32 + i;
      float dx = x - (float)(p & 15);
      float dy = y - (float)(p >> 4);
      float d2 = fmaf(dx, dx, dy*dy);
      word |= (sqrtf(d2) < 2.0f ? 1u : 0u) << i;
    }
    out[w] = invalid ? 0xFFFFFFFFu : word;
  }
  uint4* dst = (uint4*)(MB + (size_t)idx * 8);
  dst[0] = make_uint4(out[0], out[1], out[2], out[3]);
  dst[1] = make_uint4(out[4], out[5], out[6], out[7]);
}

// ============ QB16 = bf16((tq @ Wq^T + wq_b) * 0.25) ============
__global__ __launch_bounds__(256) void k_qh(
    const float* __restrict__ tf, const float* __restrict__ Wq,
    const float* __restrict__ wq_b, unsigned short* __restrict__ QB) {
  __shared__ float A[64][65];    // [c][q]
  __shared__ float W[128][65];   // [o][c]
  int b = blockIdx.y, q0 = blockIdx.x * 64, tid = threadIdx.x;
  for (int i = tid; i < 4096; i += 256) A[i >> 6][i & 63] = tf[((size_t)(b*64) + (i >> 6))*NQ + q0 + (i & 63)];
  for (int i = tid; i < 8192; i += 256) W[i >> 6][i & 63] = Wq[i];
  __syncthreads();
  int og = tid & 15, qg = tid >> 4;   // o = og*8+jo ; q = q0+qg*4+jq
  float acc[4][8] = {};
  for (int c = 0; c < 64; ++c) {
    float a[4];
#pragma unroll
    for (int jq = 0; jq < 4; ++jq) a[jq] = A[c][qg*4 + jq];
#pragma unroll
    for (int jo = 0; jo < 8; ++jo) {
      float w = W[og*8 + jo][c];
#pragma unroll
      for (int jq = 0; jq < 4; ++jq) acc[jq][jo] = fmaf(a[jq], w, acc[jq][jo]);
    }
  }
#pragma unroll
  for (int jq = 0; jq < 4; ++jq) {
    float v[8];
#pragma unroll
    for (int jo = 0; jo < 8; ++jo) v[jo] = (acc[jq][jo] + wq_b[og*8 + jo]) * 0.25f;
    uint4 pk;
    pk.x = (unsigned)f2bf(v[0]) | ((unsigned)f2bf(v[1]) << 16);
    pk.y = (unsigned)f2bf(v[2]) | ((unsigned)f2bf(v[3]) << 16);
    pk.z = (unsigned)f2bf(v[4]) | ((unsigned)f2bf(v[5]) << 16);
    pk.w = (unsigned)f2bf(v[6]) | ((unsigned)f2bf(v[7]) << 16);
    *(uint4*)(QB + ((size_t)(b*NQ) + q0 + qg*4 + jq)*128 + og*8) = pk;
  }
}

// ============ KV projection via MFMA: D[o][t] partials over 320-c slabs ======
__global__ __launch_bounds__(256, 2) void k_kvhM(
    const float* __restrict__ X, const unsigned short* __restrict__ WB,
    float* __restrict__ KVP) {
  __shared__ float XS[16][32];
  int tid = threadIdx.x;
  int t0  = blockIdx.x * 32;
  int chq = blockIdx.y;           // 0..3 c-slab
  int b   = blockIdx.z;
  int cb0 = chq * 320;
  int wid = tid >> 6, lane = tid & 63, l32 = lane & 31, hi = lane >> 5;
  f32x16 acc0, acc1;
#pragma unroll
  for (int i = 0; i < 16; ++i) { acc0[i] = 0.f; acc1[i] = 0.f; }
  int ot0 = wid * 2, ot1 = wid * 2 + 1;
  for (int ch = 0; ch < 20; ++ch) {
    int cg0 = cb0 + ch * 16;
    __syncthreads();
    {
      int v = tid;
      XS[v >> 5][v & 31] = X[((size_t)b*1280 + cg0 + (v >> 5))*NKV + t0 + (v & 31)];
      v = tid + 256;
      XS[v >> 5][v & 31] = X[((size_t)b*1280 + cg0 + (v >> 5))*NKV + t0 + (v & 31)];
    }
    __syncthreads();
    Frag fa0, fa1, fb;
    fa0.i = *(const int4*)(WB + (size_t)(ot0*32 + l32)*1280 + cg0 + hi*8);
    fa1.i = *(const int4*)(WB + (size_t)(ot1*32 + l32)*1280 + cg0 + hi*8);
#pragma unroll
    for (int j = 0; j < 4; ++j)
      fb.u[j] = f2bf2(XS[hi*8 + 2*j][l32], XS[hi*8 + 2*j + 1][l32]);
    acc0 = __builtin_amdgcn_mfma_f32_32x32x16_bf16(fa0.s, fb.s, acc0, 0, 0, 0);
    acc1 = __builtin_amdgcn_mfma_f32_32x32x16_bf16(fa1.s, fb.s, acc1, 0, 0, 0);
  }
  float* dst = KVP + ((size_t)(chq*2 + b)*NKV + t0 + l32)*256;
#pragma unroll
  for (int qd = 0; qd < 4; ++qd) {
    *(float4*)(dst + ot0*32 + qd*8 + hi*4) =
        make_float4(acc0[qd*4+0], acc0[qd*4+1], acc0[qd*4+2], acc0[qd*4+3]);
    *(float4*)(dst + ot1*32 + qd*8 + hi*4) =
        make_float4(acc1[qd*4+0], acc1[qd*4+1], acc1[qd*4+2], acc1[qd*4+3]);
  }
}

// ============ combine partials + bias -> KB16 / VB16 (bf16) ============
__global__ __launch_bounds__(256) void k_kvcomb(
    const float* __restrict__ KVP, const float* __restrict__ bkf,
    const float* __restrict__ bvf, unsigned short* __restrict__ KB,
    unsigned short* __restrict__ VB) {
  int idx = blockIdx.x * 256 + threadIdx.x;   // 2*2048*64 quads
  int og4 = idx & 63; int bt = idx >> 6;
  int b = bt >> 11, t = bt & 2047;
  int o0 = og4 * 4;
  float4 s = make_float4(0.f, 0.f, 0.f, 0.f);
#pragma unroll
  for (int ch = 0; ch < 4; ++ch) {
    float4 p = *(const float4*)(KVP + ((size_t)(ch*2 + b)*NKV + t)*256 + o0);
    s.x += p.x; s.y += p.y; s.z += p.z; s.w += p.w;
  }
  if (o0 < 128) {
    float4 bb = *(const float4*)(bkf + o0);
    s.x += bb.x; s.y += bb.y; s.z += bb.z; s.w += bb.w;
    uint2 pk;
    pk.x = (unsigned)f2bf(s.x) | ((unsigned)f2bf(s.y) << 16);
    pk.y = (unsigned)f2bf(s.z) | ((unsigned)f2bf(s.w) << 16);
    *(uint2*)(KB + (size_t)bt*128 + o0) = pk;
  } else {
    int o = o0 - 128;
    float4 bb = *(const float4*)(bvf + o);
    s.x += bb.x; s.y += bb.y; s.z += bb.z; s.w += bb.w;
    uint2 pk;
    pk.x = (unsigned)f2bf(s.x) | ((unsigned)f2bf(s.y) << 16);
    pk.y = (unsigned)f2bf(s.z) | ((unsigned)f2bf(s.w) << 16);
    *(uint2*)(VB + (size_t)bt*128 + o) = pk;
  }
}

// ============ VT: per (b,f,h) transpose V -> [32 d'][256 p], row16 = ones ====
__global__ __launch_bounds__(256) void k_vt(
    const unsigned short* __restrict__ VB, unsigned short* __restrict__ VT) {
  __shared__ unsigned short LT[16][264];
  int f = blockIdx.x, b = blockIdx.y, h = blockIdx.z;
  int tid = threadIdx.x;
  {
    const unsigned short* src = VB + ((size_t)(b*NKV) + f*256 + tid)*128 + h*16;
    Frag u1, u2;
    u1.i = *(const int4*)(src);
    u2.i = *(const int4*)(src + 8);
#pragma unroll
    for (int j = 0; j < 8; ++j) { LT[j][tid] = u1.h[j]; LT[8 + j][tid] = u2.h[j]; }
  }
  __syncthreads();
  int row = tid >> 3, pb = (tid & 7) * 32;
  unsigned ow[16];
#pragma unroll
  for (int j = 0; j < 16; ++j) {
    unsigned short v0, v1;
    if (row < 16)       { v0 = LT[row][pb + 2*j]; v1 = LT[row][pb + 2*j + 1]; }
    else if (row == 16) { v0 = 0x3F80; v1 = 0x3F80; }
    else                { v0 = 0; v1 = 0; }
    ow[j] = (unsigned)v0 | ((unsigned)v1 << 16);
  }
  unsigned short* dst = VT + (((size_t)(b*8 + f)*8 + h)*8192 + row*256 + pb);
  *(uint4*)(dst +  0) = make_uint4(ow[0],  ow[1],  ow[2],  ow[3]);
  *(uint4*)(dst +  8) = make_uint4(ow[4],  ow[5],  ow[6],  ow[7]);
  *(uint4*)(dst + 16) = make_uint4(ow[8],  ow[9],  ow[10], ow[11]);
  *(uint4*)(dst + 24) = make_uint4(ow[12], ow[13], ow[14], ow[15]);
}

// ============ MFMA attention: S^T=mfma(K,Q); exp; pack; attn^T=mfma(VT,P^T) ==
// wave: (qtile of 32, pixel-half); ones-row of VT yields softmax denom in d'=16
__global__ __launch_bounds__(256, 3) void k_attnM(
    const unsigned short* __restrict__ QB, const unsigned short* __restrict__ KB,
    const unsigned short* __restrict__ VT, const unsigned* __restrict__ MB,
    float* __restrict__ ATTN) {
  __shared__ float MRG[2][32][32];
  int tid = threadIdx.x;
  int wid = tid >> 6, lane = tid & 63, l32 = lane & 31, hi = lane >> 5;
  int bh = blockIdx.y, b = bh >> 3, h = bh & 7;
  int qts = wid >> 1, ph = wid & 1;
  int qbase = (blockIdx.x * 2 + qts) * 32;
  int ph4 = ph * 4;

  Frag fq;
  fq.i = *(const int4*)(QB + ((size_t)(b*NQ) + qbase + l32)*128 + h*16 + hi*8);

  f32x16 acc;
#pragma unroll
  for (int i = 0; i < 16; ++i) acc[i] = 0.f;
  f32x16 zz;
#pragma unroll
  for (int i = 0; i < 16; ++i) zz[i] = 0.f;

  for (int f = 0; f < 8; ++f) {
    uint4 mv = *(const uint4*)(MB + ((size_t)((b*8 + f)*NQ) + qbase + l32)*8 + ph4);
    unsigned mwa[4] = {mv.x, mv.y, mv.z, mv.w};
    const unsigned short* KBf = KB + ((size_t)(b*NKV) + f*256)*128 + h*16;
    const unsigned short* VTf = VT + (((size_t)(b*8 + f)*8 + h)*8192) + l32*256;
#pragma unroll
    for (int c = 0; c < 4; ++c) {
      int cg = ph4 + c;
      Frag fk;
      fk.i = *(const int4*)(KBf + (size_t)(cg*32 + l32)*128 + hi*8);
      f32x16 S = __builtin_amdgcn_mfma_f32_32x32x16_bf16(fk.s, fq.s, zz, 0, 0, 0);
      unsigned w = mwa[c];
      float e[16];
#pragma unroll
      for (int r = 0; r < 16; ++r) {
        int rl = (r & 3) + 8*(r >> 2) + 4*hi;
        e[r] = ((w >> rl) & 1u) ? 0.f : __expf(S[r]);
      }
#pragma unroll
      for (int half = 0; half < 2; ++half) {
        int e0 = half * 8;
        unsigned x0 = f2bf2(e[e0+0], e[e0+1]);
        unsigned y0 = f2bf2(e[e0+4], e[e0+5]);
        plswap(x0, y0);
        unsigned x1 = f2bf2(e[e0+2], e[e0+3]);
        unsigned y1 = f2bf2(e[e0+6], e[e0+7]);
        plswap(x1, y1);
        Frag fp; fp.u[0] = x0; fp.u[1] = x1; fp.u[2] = y0; fp.u[3] = y1;
        Frag fv;
        fv.i = *(const int4*)(VTf + cg*32 + half*16 + hi*8);
        acc = __builtin_amdgcn_mfma_f32_32x32x16_bf16(fv.s, fp.s, acc, 0, 0, 0);
      }
    }
  }
  // merge pixel-halves via LDS
  if (ph == 1) {
#pragma unroll
    for (int r = 0; r < 16; ++r) {
      int dp = (r & 3) + 8*(r >> 2) + 4*hi;
      MRG[qts][dp][l32] = acc[r];
    }
  }
  __syncthreads();
  if (ph == 0) {
#pragma unroll
    for (int r = 0; r < 16; ++r) {
      int dp = (r & 3) + 8*(r >> 2) + 4*hi;
      acc[r] += MRG[qts][dp][l32];
    }
    float l = __shfl(acc[8], l32);     // d'=16 (ones row) lives on hi=0 lanes
    float inv = 1.0f / l;
    float* Ap = ATTN + ((size_t)(b*NQ) + qbase + l32)*128 + h*16;
    *(float4*)(Ap + 4*hi)     = make_float4(acc[0]*inv, acc[1]*inv, acc[2]*inv, acc[3]*inv);
    *(float4*)(Ap + 8 + 4*hi) = make_float4(acc[4]*inv, acc[5]*inv, acc[6]*inv, acc[7]*inv);
  }
}

// ============ out = ATTN @ Wo^T + bo, stored (b, c, n) ============
__global__ __launch_bounds__(256) void k_out(
    const float* __restrict__ ATTN, const float* __restrict__ Wo,
    const float* __restrict__ bo, float* __restrict__ out) {
  __shared__ float A[64][129];
  __shared__ float W[64][129];
  int b = blockIdx.y, n0 = blockIdx.x * 64, tid = threadIdx.x;
  for (int i = tid; i < 8192; i += 256) { int n = i >> 7, o = i & 127; A[n][o] = ATTN[((size_t)(b*NQ) + n0 + n)*128 + o]; }
  for (int i = tid; i < 8192; i += 256) { int c = i >> 7, o = i & 127; W[c][o] = Wo[i]; }
  __syncthreads();
  int ng = tid & 31, cg = tid >> 5;
  float acc[2][8] = {};
  for (int o = 0; o < 128; ++o) {
    float a0 = A[ng][o], a1 = A[ng + 32][o];
#pragma unroll
    for (int jc = 0; jc < 8; ++jc) {
      float w = W[cg*8 + jc][o];
      acc[0][jc] = fmaf(a0, w, acc[0][jc]);
      acc[1][jc] = fmaf(a1, w, acc[1][jc]);
    }
  }
#pragma unroll
  for (int jn = 0; jn < 2; ++jn)
#pragma unroll
    for (int jc = 0; jc < 8; ++jc) {
      int c = cg*8 + jc;
      out[((size_t)(b*64) + c)*NQ + n0 + ng + 32*jn] = acc[jn][jc] + bo[c];
    }
}

extern "C" void kernel_launch(void* const* d_in, const int* in_sizes, int n_in,
                              void* d_out, int out_size, void* d_ws, size_t ws_size,
                              hipStream_t stream) {
  const float* tf     = (const float*)d_in[0];
  const float* imf    = (const float*)d_in[1];
  const float* proj   = (const float*)d_in[2];
  const float* vfr    = (const float*)d_in[3];
  const float* conv_w = (const float*)d_in[4];
  const float* conv_b = (const float*)d_in[5];
  const float* q_w    = (const float*)d_in[6];
  const float* k_w    = (const float*)d_in[7];
  const float* k_b    = (const float*)d_in[8];
  const float* v_w    = (const float*)d_in[9];
  const float* v_b    = (const float*)d_in[10];
  const float* wq     = (const float*)d_in[11];
  const float* wq_b   = (const float*)d_in[12];
  const float* wk     = (const float*)d_in[13];
  const float* wk_b   = (const float*)d_in[14];
  const float* wv     = (const float*)d_in[15];
  const float* wv_b   = (const float*)d_in[16];
  const float* aow    = (const float*)d_in[17];
  const float* aob    = (const float*)d_in[18];
  const float* out_w  = (const float*)d_in[19];
  const float* out_b  = (const float*)d_in[20];
  float* ws  = (float*)d_ws;
  float* out = (float*)d_out;
  unsigned short* WB = (unsigned short*)(ws + OFF_WB);
  unsigned short* QB = (unsigned short*)(ws + OFF_QB);
  unsigned short* KB = (unsigned short*)(ws + OFF_KB);
  unsigned short* VB = (unsigned short*)(ws + OFF_VB);
  unsigned short* VT = (unsigned short*)(ws + OFF_VT);
  unsigned* MB = (unsigned*)(ws + OFF_MB);

  k_fuse1<<<dim3(578), dim3(256), 0, stream>>>(wk, k_w, wv, v_w, wq, q_w, out_w, aow,
                                               k_b, wk_b, v_b, wv_b, aob, out_b, ws);
  k_fuse2<<<dim3(5,16,2), dim3(256), 0, stream>>>(ws+OFF_TK, ws+OFF_TV, conv_w, WB);
  k_biasf<<<dim3(1), dim3(256), 0, stream>>>(ws+OFF_TK, ws+OFF_TV, conv_b, ws+OFF_BK1, ws+OFF_BV1,
                                             ws+OFF_BKF, ws+OFF_BVF);
  k_maskbits<<<dim3(192), dim3(256), 0, stream>>>(proj, vfr, MB);
  k_qh<<<dim3(48,2), dim3(256), 0, stream>>>(tf, ws+OFF_WQ, wq_b, QB);
  k_kvhM<<<dim3(64,4,2), dim3(256), 0, stream>>>(imf, WB, ws+OFF_KVP);
  k_kvcomb<<<dim3(1024), dim3(256), 0, stream>>>(ws+OFF_KVP, ws+OFF_BKF, ws+OFF_BVF, KB, VB);
  k_vt<<<dim3(8,2,8), dim3(256), 0, stream>>>(VB, VT);
  k_attnM<<<dim3(48,16), dim3(256), 0, stream>>>(QB, KB, VT, MB, ws+OFF_ATTN);
  k_out<<<dim3(48,2), dim3(256), 0, stream>>>(ws+OFF_ATTN, ws+OFF_WO, ws+OFF_BO, out);
}

// Round 11
// 253.523 us; speedup vs baseline: 1.5758x; 1.1309x over previous
//
#include <hip/hip_runtime.h>

// ---------------- problem constants ----------------
#define NQ 3072        // 3*32*32 triplane queries
#define NPIX 256
#define NKV 2048
#define NH 8

typedef __attribute__((ext_vector_type(8))) short short8;
typedef __attribute__((ext_vector_type(16))) float f32x16;

union Frag {
  int4 i;
  short8 s;
  unsigned u[4];
  unsigned short h[8];
};

__device__ inline unsigned short f2bf(float x) {
  unsigned u = __float_as_uint(x);
  return (unsigned short)((u + 0x7FFFu + ((u >> 16) & 1u)) >> 16);
}
__device__ inline unsigned f2bf2(float lo, float hi) {
  unsigned r;
  asm("v_cvt_pk_bf16_f32 %0, %1, %2" : "=v"(r) : "v"(lo), "v"(hi));
  return r;
}
__device__ inline void plswap(unsigned& a, unsigned& b) {
  asm("v_permlane32_swap_b32 %0, %1" : "+v"(a), "+v"(b));
}

// ---------------- workspace layout (float offsets) ----------------
#define OFF_TK      0u         // 128*512 fp32   wk@k_w
#define OFF_TV      65536u     // 128*512 fp32   wv@v_w
#define OFF_WQ      131072u    // 128*64 fp32    wq@q_w
#define OFF_WO      139264u    // 64*128 fp32    out_w@attn_out_w
#define OFF_BK1     147456u    // 128
#define OFF_BV1     147584u    // 128
#define OFF_BO      147712u    // 64
#define OFF_WB      147776u    // bf16 256*1280  fused conv->K|V weight
#define OFF_BKF     311616u    // 128 fp32
#define OFF_BVF     311744u    // 128 fp32
#define OFF_MB      311872u    // u32 2*8*3072*8 visibility bits
#define OFF_QB      705088u    // bf16 2*3072*128 (scale folded)
#define OFF_KVP     1098304u   // fp32 4ch*2b*2048*256 partials
#define OFF_KB      5292608u   // bf16 2*2048*128
#define OFF_VB      5554752u   // bf16 2*2048*128
#define OFF_VT      5816896u   // bf16 2b*8f*8h*32*256 V^T augmented (row16=1)
#define OFF_ATTN    6341184u   // fp32 2*3072*128
#define OFF_WP      7127616u   // fp32 2ks*256*1280 fuse2 partials

// ============ small fused-weight products (all K=128 dots) ============
__global__ __launch_bounds__(256) void k_fuse1(
    const float* __restrict__ wk, const float* __restrict__ k_w,
    const float* __restrict__ wv, const float* __restrict__ v_w,
    const float* __restrict__ wq, const float* __restrict__ q_w,
    const float* __restrict__ out_w, const float* __restrict__ aow,
    const float* __restrict__ k_b, const float* __restrict__ wk_b,
    const float* __restrict__ v_b, const float* __restrict__ wv_b,
    const float* __restrict__ aob, const float* __restrict__ out_b,
    float* __restrict__ ws) {
  int idx = blockIdx.x * 256 + threadIdx.x;
  if (idx < 131072) {                 // Tk / Tv : [o<128][m<512]
    const float* Wb = (idx < 65536) ? wk : wv;
    const float* Ws = (idx < 65536) ? k_w : v_w;
    float* dst = ws + ((idx < 65536) ? OFF_TK : OFF_TV);
    int t = idx & 65535; int o = t >> 9, m = t & 511;
    float s = 0.f;
#pragma unroll 8
    for (int j = 0; j < 128; ++j) s = fmaf(Wb[o*128+j], Ws[j*512+m], s);
    dst[t] = s;
  } else if (idx < 139264) {          // Wq : [o<128][c<64]
    int t = idx - 131072; int o = t >> 6, c = t & 63;
    float s = 0.f;
#pragma unroll 8
    for (int j = 0; j < 128; ++j) s = fmaf(wq[o*128+j], q_w[j*64+c], s);
    ws[OFF_WQ + t] = s;
  } else if (idx < 147456) {          // Wo : [c<64][o<128]
    int t = idx - 139264; int c = t >> 7, o = t & 127;
    float s = 0.f;
#pragma unroll 8
    for (int j = 0; j < 128; ++j) s = fmaf(out_w[c*128+j], aow[j*128+o], s);
    ws[OFF_WO + t] = s;
  } else if (idx < 147712) {          // bk1 / bv1
    int t = idx - 147456; int o = t & 127;
    const float* Wb = (t < 128) ? wk : wv;
    const float* bi = (t < 128) ? k_b : v_b;
    const float* ba = (t < 128) ? wk_b : wv_b;
    float s = 0.f;
    for (int j = 0; j < 128; ++j) s = fmaf(Wb[o*128+j], bi[j], s);
    ws[(t < 128 ? OFF_BK1 : OFF_BV1) + o] = s + ba[o];
  } else if (idx < 147776) {          // bo
    int c = idx - 147712;
    float s = 0.f;
    for (int j = 0; j < 128; ++j) s = fmaf(out_w[c*128+j], aob[j], s);
    ws[OFF_BO + c] = s + out_b[c];
  }
}

// ============ fuse2 partials: WP[ks][256][1280] = [Tk;Tv] @ conv_w (K-split 2)
// 640 blocks (2.5/CU): latency-hiding fix for the measured 50-65us k_fuse2.
__global__ __launch_bounds__(256) void k_fuse2p(
    const float* __restrict__ Tk, const float* __restrict__ Tv,
    const float* __restrict__ conv_w, float* __restrict__ WP) {
  __shared__ float Ts[256][20];   // [m][r], pad 20 -> aligned float4, b128 broadcast
  int tid = threadIdx.x;
  int x = blockIdx.x, y = blockIdx.y, ks = blockIdx.z;
  const float* T = (y < 8) ? (Tk + (y*16)*512) : (Tv + ((y-8)*16)*512);
#pragma unroll
  for (int k = 0; k < 16; ++k) {
    int i = tid + k*256;
    int m = i & 255, r = i >> 8;
    Ts[m][r] = T[r*512 + ks*256 + m];
  }
  __syncthreads();
  int col = x*64 + (tid & 63);
  int rgrp = (tid >> 6) * 4;
  float acc0=0.f, acc1=0.f, acc2=0.f, acc3=0.f;
  const float* cw = conv_w + (size_t)(ks*256)*1280 + col;
  for (int m4 = 0; m4 < 64; ++m4) {
    float w0 = cw[(size_t)(m4*4+0)*1280];
    float w1 = cw[(size_t)(m4*4+1)*1280];
    float w2 = cw[(size_t)(m4*4+2)*1280];
    float w3 = cw[(size_t)(m4*4+3)*1280];
    float4 a0 = *(const float4*)&Ts[m4*4+0][rgrp];
    float4 a1 = *(const float4*)&Ts[m4*4+1][rgrp];
    float4 a2 = *(const float4*)&Ts[m4*4+2][rgrp];
    float4 a3 = *(const float4*)&Ts[m4*4+3][rgrp];
    acc0 = fmaf(a3.x,w3,fmaf(a2.x,w2,fmaf(a1.x,w1,fmaf(a0.x,w0,acc0))));
    acc1 = fmaf(a3.y,w3,fmaf(a2.y,w2,fmaf(a1.y,w1,fmaf(a0.y,w0,acc1))));
    acc2 = fmaf(a3.z,w3,fmaf(a2.z,w2,fmaf(a1.z,w1,fmaf(a0.z,w0,acc2))));
    acc3 = fmaf(a3.w,w3,fmaf(a2.w,w2,fmaf(a1.w,w1,fmaf(a0.w,w0,acc3))));
  }
  float* dst = WP + ((size_t)(ks*256 + y*16 + rgrp))*1280 + col;
  dst[0]    = acc0;
  dst[1280] = acc1;
  dst[2560] = acc2;
  dst[3840] = acc3;
}

// ============ combine fuse2 partials -> WB bf16 ============
__global__ __launch_bounds__(256) void k_wcomb(
    const float* __restrict__ WP, unsigned short* __restrict__ WB) {
  int idx = blockIdx.x * 256 + threadIdx.x;   // 163840 (2 cols each)
  int c2 = idx % 640, r = idx / 640;
  size_t o = (size_t)r*1280 + c2*2;
  float2 p0 = *(const float2*)(WP + o);
  float2 p1 = *(const float2*)(WP + 327680 + o);
  unsigned pk = (unsigned)f2bf(p0.x + p1.x) | ((unsigned)f2bf(p0.y + p1.y) << 16);
  *(unsigned*)(WB + o) = pk;
}

// ============ fused biases through conv ============
__global__ __launch_bounds__(256) void k_biasf(
    const float* __restrict__ Tk, const float* __restrict__ Tv,
    const float* __restrict__ conv_b, const float* __restrict__ bk1,
    const float* __restrict__ bv1, float* __restrict__ bkf, float* __restrict__ bvf) {
  int tid = threadIdx.x;
  const float* T = (tid < 128) ? Tk : Tv;
  int o = tid & 127;
  float s = 0.f;
  for (int m = 0; m < 512; ++m) s = fmaf(T[o*512+m], conv_b[m], s);
  if (tid < 128) bkf[o] = s + bk1[o]; else bvf[o] = s + bv1[o];
}

// ============ visibility mask bits per (b,frame,q): 8 x u32 ============
__global__ __launch_bounds__(256) void k_maskbits(
    const float* __restrict__ proj, const float* __restrict__ vfr,
    unsigned* __restrict__ MB) {
  int idx = blockIdx.x * 256 + threadIdx.x;   // (b*8+f)*NQ + q
  int q = idx % NQ; int bk = idx / NQ;
  int plane = q >> 10, rem = q & 1023;
  float fi = (float)(rem >> 5), fj = (float)(rem & 31);
  float cx, cy, cz;
  if (plane == 0)      { cx = fj;    cy = 15.5f; cz = fi; }
  else if (plane == 1) { cx = fj;    cy = fi;    cz = 15.5f; }
  else                 { cx = 15.5f; cy = fj;    cz = fi; }
  cx = ((cx / 31.0f) - 0.5f) * 2.0f * 1.10001f;
  cy = ((cy / 31.0f) - 0.5f) * 2.0f * 1.10001f;
  cz = ((cz / 31.0f) - 0.5f) * 2.0f * 1.10001f;
  const float* P = proj + bk * 16;
  float c0 = cx*P[0] + cy*P[1] + cz*P[2] + P[3];
  float c1 = cx*P[4] + cy*P[5] + cz*P[6] + P[7];
  float c2 = cx*P[8] + cy*P[9] + cz*P[10] + P[11];
  float x = (c0 / c2) / 223.0f * 15.0f;
  float y = (c1 / c2) / 223.0f * 15.0f;
  bool invalid = (1.0f - vfr[bk]) > 0.0f;
  unsigned out[8];
#pragma unroll
  for (int w = 0; w < 8; ++w) {
    unsigned word = 0;
#pragma unroll
    for (int i = 0; i < 32; ++i) {
      int p = w*32 + i;
      float dx = x - (float)(p & 15);
      float dy = y - (float)(p >> 4);
      float d2 = fmaf(dx, dx, dy*dy);
      word |= (sqrtf(d2) < 2.0f ? 1u : 0u) << i;
    }
    out[w] = invalid ? 0xFFFFFFFFu : word;
  }
  uint4* dst = (uint4*)(MB + (size_t)idx * 8);
  dst[0] = make_uint4(out[0], out[1], out[2], out[3]);
  dst[1] = make_uint4(out[4], out[5], out[6], out[7]);
}

// ============ QB16 = bf16((tq @ Wq^T + wq_b) * 0.25) ============
__global__ __launch_bounds__(256) void k_qh(
    const float* __restrict__ tf, const float* __restrict__ Wq,
    const float* __restrict__ wq_b, unsigned short* __restrict__ QB) {
  __shared__ float A[64][65];    // [c][q]
  __shared__ float W[128][65];   // [o][c]
  int b = blockIdx.y, q0 = blockIdx.x * 64, tid = threadIdx.x;
  for (int i = tid; i < 4096; i += 256) A[i >> 6][i & 63] = tf[((size_t)(b*64) + (i >> 6))*NQ + q0 + (i & 63)];
  for (int i = tid; i < 8192; i += 256) W[i >> 6][i & 63] = Wq[i];
  __syncthreads();
  int og = tid & 15, qg = tid >> 4;   // o = og*8+jo ; q = q0+qg*4+jq
  float acc[4][8] = {};
  for (int c = 0; c < 64; ++c) {
    float a[4];
#pragma unroll
    for (int jq = 0; jq < 4; ++jq) a[jq] = A[c][qg*4 + jq];
#pragma unroll
    for (int jo = 0; jo < 8; ++jo) {
      float w = W[og*8 + jo][c];
#pragma unroll
      for (int jq = 0; jq < 4; ++jq) acc[jq][jo] = fmaf(a[jq], w, acc[jq][jo]);
    }
  }
#pragma unroll
  for (int jq = 0; jq < 4; ++jq) {
    float v[8];
#pragma unroll
    for (int jo = 0; jo < 8; ++jo) v[jo] = (acc[jq][jo] + wq_b[og*8 + jo]) * 0.25f;
    uint4 pk;
    pk.x = (unsigned)f2bf(v[0]) | ((unsigned)f2bf(v[1]) << 16);
    pk.y = (unsigned)f2bf(v[2]) | ((unsigned)f2bf(v[3]) << 16);
    pk.z = (unsigned)f2bf(v[4]) | ((unsigned)f2bf(v[5]) << 16);
    pk.w = (unsigned)f2bf(v[6]) | ((unsigned)f2bf(v[7]) << 16);
    *(uint4*)(QB + ((size_t)(b*NQ) + q0 + qg*4 + jq)*128 + og*8) = pk;
  }
}

// ============ KV projection via MFMA: D[o][t] partials over 320-c slabs ======
__global__ __launch_bounds__(256, 2) void k_kvhM(
    const float* __restrict__ X, const unsigned short* __restrict__ WB,
    float* __restrict__ KVP) {
  __shared__ float XS[16][32];
  int tid = threadIdx.x;
  int t0  = blockIdx.x * 32;
  int chq = blockIdx.y;           // 0..3 c-slab
  int b   = blockIdx.z;
  int cb0 = chq * 320;
  int wid = tid >> 6, lane = tid & 63, l32 = lane & 31, hi = lane >> 5;
  f32x16 acc0, acc1;
#pragma unroll
  for (int i = 0; i < 16; ++i) { acc0[i] = 0.f; acc1[i] = 0.f; }
  int ot0 = wid * 2, ot1 = wid * 2 + 1;
  for (int ch = 0; ch < 20; ++ch) {
    int cg0 = cb0 + ch * 16;
    __syncthreads();
    {
      int v = tid;
      XS[v >> 5][v & 31] = X[((size_t)b*1280 + cg0 + (v >> 5))*NKV + t0 + (v & 31)];
      v = tid + 256;
      XS[v >> 5][v & 31] = X[((size_t)b*1280 + cg0 + (v >> 5))*NKV + t0 + (v & 31)];
    }
    __syncthreads();
    Frag fa0, fa1, fb;
    fa0.i = *(const int4*)(WB + (size_t)(ot0*32 + l32)*1280 + cg0 + hi*8);
    fa1.i = *(const int4*)(WB + (size_t)(ot1*32 + l32)*1280 + cg0 + hi*8);
#pragma unroll
    for (int j = 0; j < 4; ++j)
      fb.u[j] = f2bf2(XS[hi*8 + 2*j][l32], XS[hi*8 + 2*j + 1][l32]);
    acc0 = __builtin_amdgcn_mfma_f32_32x32x16_bf16(fa0.s, fb.s, acc0, 0, 0, 0);
    acc1 = __builtin_amdgcn_mfma_f32_32x32x16_bf16(fa1.s, fb.s, acc1, 0, 0, 0);
  }
  float* dst = KVP + ((size_t)(chq*2 + b)*NKV + t0 + l32)*256;
#pragma unroll
  for (int qd = 0; qd < 4; ++qd) {
    *(float4*)(dst + ot0*32 + qd*8 + hi*4) =
        make_float4(acc0[qd*4+0], acc0[qd*4+1], acc0[qd*4+2], acc0[qd*4+3]);
    *(float4*)(dst + ot1*32 + qd*8 + hi*4) =
        make_float4(acc1[qd*4+0], acc1[qd*4+1], acc1[qd*4+2], acc1[qd*4+3]);
  }
}

// ============ combine partials + bias -> KB16 / VB16 (bf16) ============
__global__ __launch_bounds__(256) void k_kvcomb(
    const float* __restrict__ KVP, const float* __restrict__ bkf,
    const float* __restrict__ bvf, unsigned short* __restrict__ KB,
    unsigned short* __restrict__ VB) {
  int idx = blockIdx.x * 256 + threadIdx.x;   // 2*2048*64 quads
  int og4 = idx & 63; int bt = idx >> 6;
  int b = bt >> 11, t = bt & 2047;
  int o0 = og4 * 4;
  float4 s = make_float4(0.f, 0.f, 0.f, 0.f);
#pragma unroll
  for (int ch = 0; ch < 4; ++ch) {
    float4 p = *(const float4*)(KVP + ((size_t)(ch*2 + b)*NKV + t)*256 + o0);
    s.x += p.x; s.y += p.y; s.z += p.z; s.w += p.w;
  }
  if (o0 < 128) {
    float4 bb = *(const float4*)(bkf + o0);
    s.x += bb.x; s.y += bb.y; s.z += bb.z; s.w += bb.w;
    uint2 pk;
    pk.x = (unsigned)f2bf(s.x) | ((unsigned)f2bf(s.y) << 16);
    pk.y = (unsigned)f2bf(s.z) | ((unsigned)f2bf(s.w) << 16);
    *(uint2*)(KB + (size_t)bt*128 + o0) = pk;
  } else {
    int o = o0 - 128;
    float4 bb = *(const float4*)(bvf + o);
    s.x += bb.x; s.y += bb.y; s.z += bb.z; s.w += bb.w;
    uint2 pk;
    pk.x = (unsigned)f2bf(s.x) | ((unsigned)f2bf(s.y) << 16);
    pk.y = (unsigned)f2bf(s.z) | ((unsigned)f2bf(s.w) << 16);
    *(uint2*)(VB + (size_t)bt*128 + o) = pk;
  }
}

// ============ VT: per (b,f,h) transpose V -> [32 d'][256 p], row16 = ones ====
__global__ __launch_bounds__(256) void k_vt(
    const unsigned short* __restrict__ VB, unsigned short* __restrict__ VT) {
  __shared__ unsigned short LT[16][264];
  int f = blockIdx.x, b = blockIdx.y, h = blockIdx.z;
  int tid = threadIdx.x;
  {
    const unsigned short* src = VB + ((size_t)(b*NKV) + f*256 + tid)*128 + h*16;
    Frag u1, u2;
    u1.i = *(const int4*)(src);
    u2.i = *(const int4*)(src + 8);
#pragma unroll
    for (int j = 0; j < 8; ++j) { LT[j][tid] = u1.h[j]; LT[8 + j][tid] = u2.h[j]; }
  }
  __syncthreads();
  int row = tid >> 3, pb = (tid & 7) * 32;
  unsigned ow[16];
#pragma unroll
  for (int j = 0; j < 16; ++j) {
    unsigned short v0, v1;
    if (row < 16)       { v0 = LT[row][pb + 2*j]; v1 = LT[row][pb + 2*j + 1]; }
    else if (row == 16) { v0 = 0x3F80; v1 = 0x3F80; }
    else                { v0 = 0; v1 = 0; }
    ow[j] = (unsigned)v0 | ((unsigned)v1 << 16);
  }
  unsigned short* dst = VT + (((size_t)(b*8 + f)*8 + h)*8192 + row*256 + pb);
  *(uint4*)(dst +  0) = make_uint4(ow[0],  ow[1],  ow[2],  ow[3]);
  *(uint4*)(dst +  8) = make_uint4(ow[4],  ow[5],  ow[6],  ow[7]);
  *(uint4*)(dst + 16) = make_uint4(ow[8],  ow[9],  ow[10], ow[11]);
  *(uint4*)(dst + 24) = make_uint4(ow[12], ow[13], ow[14], ow[15]);
}

// ============ MFMA attention: S^T=mfma(K,Q); exp; pack; attn^T=mfma(VT,P^T) ==
// wave: (qtile of 32, pixel-half); ones-row of VT yields softmax denom in d'=16
__global__ __launch_bounds__(256, 3) void k_attnM(
    const unsigned short* __restrict__ QB, const unsigned short* __restrict__ KB,
    const unsigned short* __restrict__ VT, const unsigned* __restrict__ MB,
    float* __restrict__ ATTN) {
  __shared__ float MRG[2][32][32];
  int tid = threadIdx.x;
  int wid = tid >> 6, lane = tid & 63, l32 = lane & 31, hi = lane >> 5;
  int bh = blockIdx.y, b = bh >> 3, h = bh & 7;
  int qts = wid >> 1, ph = wid & 1;
  int qbase = (blockIdx.x * 2 + qts) * 32;
  int ph4 = ph * 4;

  Frag fq;
  fq.i = *(const int4*)(QB + ((size_t)(b*NQ) + qbase + l32)*128 + h*16 + hi*8);

  f32x16 acc;
#pragma unroll
  for (int i = 0; i < 16; ++i) acc[i] = 0.f;
  f32x16 zz;
#pragma unroll
  for (int i = 0; i < 16; ++i) zz[i] = 0.f;

  for (int f = 0; f < 8; ++f) {
    uint4 mv = *(const uint4*)(MB + ((size_t)((b*8 + f)*NQ) + qbase + l32)*8 + ph4);
    unsigned mwa[4] = {mv.x, mv.y, mv.z, mv.w};
    const unsigned short* KBf = KB + ((size_t)(b*NKV) + f*256)*128 + h*16;
    const unsigned short* VTf = VT + (((size_t)(b*8 + f)*8 + h)*8192) + l32*256;
#pragma unroll
    for (int c = 0; c < 4; ++c) {
      int cg = ph4 + c;
      Frag fk;
      fk.i = *(const int4*)(KBf + (size_t)(cg*32 + l32)*128 + hi*8);
      f32x16 S = __builtin_amdgcn_mfma_f32_32x32x16_bf16(fk.s, fq.s, zz, 0, 0, 0);
      unsigned w = mwa[c];
      float e[16];
#pragma unroll
      for (int r = 0; r < 16; ++r) {
        int rl = (r & 3) + 8*(r >> 2) + 4*hi;
        e[r] = ((w >> rl) & 1u) ? 0.f : __expf(S[r]);
      }
#pragma unroll
      for (int half = 0; half < 2; ++half) {
        int e0 = half * 8;
        unsigned x0 = f2bf2(e[e0+0], e[e0+1]);
        unsigned y0 = f2bf2(e[e0+4], e[e0+5]);
        plswap(x0, y0);
        unsigned x1 = f2bf2(e[e0+2], e[e0+3]);
        unsigned y1 = f2bf2(e[e0+6], e[e0+7]);
        plswap(x1, y1);
        Frag fp; fp.u[0] = x0; fp.u[1] = x1; fp.u[2] = y0; fp.u[3] = y1;
        Frag fv;
        fv.i = *(const int4*)(VTf + cg*32 + half*16 + hi*8);
        acc = __builtin_amdgcn_mfma_f32_32x32x16_bf16(fv.s, fp.s, acc, 0, 0, 0);
      }
    }
  }
  // merge pixel-halves via LDS
  if (ph == 1) {
#pragma unroll
    for (int r = 0; r < 16; ++r) {
      int dp = (r & 3) + 8*(r >> 2) + 4*hi;
      MRG[qts][dp][l32] = acc[r];
    }
  }
  __syncthreads();
  if (ph == 0) {
#pragma unroll
    for (int r = 0; r < 16; ++r) {
      int dp = (r & 3) + 8*(r >> 2) + 4*hi;
      acc[r] += MRG[qts][dp][l32];
    }
    float l = __shfl(acc[8], l32);     // d'=16 (ones row) lives on hi=0 lanes
    float inv = 1.0f / l;
    float* Ap = ATTN + ((size_t)(b*NQ) + qbase + l32)*128 + h*16;
    *(float4*)(Ap + 4*hi)     = make_float4(acc[0]*inv, acc[1]*inv, acc[2]*inv, acc[3]*inv);
    *(float4*)(Ap + 8 + 4*hi) = make_float4(acc[4]*inv, acc[5]*inv, acc[6]*inv, acc[7]*inv);
  }
}

// ============ out = ATTN @ Wo^T + bo, stored (b, c, n) ============
__global__ __launch_bounds__(256) void k_out(
    const float* __restrict__ ATTN, const float* __restrict__ Wo,
    const float* __restrict__ bo, float* __restrict__ out) {
  __shared__ float A[64][129];
  __shared__ float W[64][129];
  int b = blockIdx.y, n0 = blockIdx.x * 64, tid = threadIdx.x;
  for (int i = tid; i < 8192; i += 256) { int n = i >> 7, o = i & 127; A[n][o] = ATTN[((size_t)(b*NQ) + n0 + n)*128 + o]; }
  for (int i = tid; i < 8192; i += 256) { int c = i >> 7, o = i & 127; W[c][o] = Wo[i]; }
  __syncthreads();
  int ng = tid & 31, cg = tid >> 5;
  float acc[2][8] = {};
  for (int o = 0; o < 128; ++o) {
    float a0 = A[ng][o], a1 = A[ng + 32][o];
#pragma unroll
    for (int jc = 0; jc < 8; ++jc) {
      float w = W[cg*8 + jc][o];
      acc[0][jc] = fmaf(a0, w, acc[0][jc]);
      acc[1][jc] = fmaf(a1, w, acc[1][jc]);
    }
  }
#pragma unroll
  for (int jn = 0; jn < 2; ++jn)
#pragma unroll
    for (int jc = 0; jc < 8; ++jc) {
      int c = cg*8 + jc;
      out[((size_t)(b*64) + c)*NQ + n0 + ng + 32*jn] = acc[jn][jc] + bo[c];
    }
}

extern "C" void kernel_launch(void* const* d_in, const int* in_sizes, int n_in,
                              void* d_out, int out_size, void* d_ws, size_t ws_size,
                              hipStream_t stream) {
  const float* tf     = (const float*)d_in[0];
  const float* imf    = (const float*)d_in[1];
  const float* proj   = (const float*)d_in[2];
  const float* vfr    = (const float*)d_in[3];
  const float* conv_w = (const float*)d_in[4];
  const float* conv_b = (const float*)d_in[5];
  const float* q_w    = (const float*)d_in[6];
  const float* k_w    = (const float*)d_in[7];
  const float* k_b    = (const float*)d_in[8];
  const float* v_w    = (const float*)d_in[9];
  const float* v_b    = (const float*)d_in[10];
  const float* wq     = (const float*)d_in[11];
  const float* wq_b   = (const float*)d_in[12];
  const float* wk     = (const float*)d_in[13];
  const float* wk_b   = (const float*)d_in[14];
  const float* wv     = (const float*)d_in[15];
  const float* wv_b   = (const float*)d_in[16];
  const float* aow    = (const float*)d_in[17];
  const float* aob    = (const float*)d_in[18];
  const float* out_w  = (const float*)d_in[19];
  const float* out_b  = (const float*)d_in[20];
  float* ws  = (float*)d_ws;
  float* out = (float*)d_out;
  unsigned short* WB = (unsigned short*)(ws + OFF_WB);
  unsigned short* QB = (unsigned short*)(ws + OFF_QB);
  unsigned short* KB = (unsigned short*)(ws + OFF_KB);
  unsigned short* VB = (unsigned short*)(ws + OFF_VB);
  unsigned short* VT = (unsigned short*)(ws + OFF_VT);
  unsigned* MB = (unsigned*)(ws + OFF_MB);

  k_fuse1<<<dim3(578), dim3(256), 0, stream>>>(wk, k_w, wv, v_w, wq, q_w, out_w, aow,
                                               k_b, wk_b, v_b, wv_b, aob, out_b, ws);
  k_fuse2p<<<dim3(20,16,2), dim3(256), 0, stream>>>(ws+OFF_TK, ws+OFF_TV, conv_w, ws+OFF_WP);
  k_wcomb<<<dim3(640), dim3(256), 0, stream>>>(ws+OFF_WP, WB);
  k_biasf<<<dim3(1), dim3(256), 0, stream>>>(ws+OFF_TK, ws+OFF_TV, conv_b, ws+OFF_BK1, ws+OFF_BV1,
                                             ws+OFF_BKF, ws+OFF_BVF);
  k_maskbits<<<dim3(192), dim3(256), 0, stream>>>(proj, vfr, MB);
  k_qh<<<dim3(48,2), dim3(256), 0, stream>>>(tf, ws+OFF_WQ, wq_b, QB);
  k_kvhM<<<dim3(64,4,2), dim3(256), 0, stream>>>(imf, WB, ws+OFF_KVP);
  k_kvcomb<<<dim3(1024), dim3(256), 0, stream>>>(ws+OFF_KVP, ws+OFF_BKF, ws+OFF_BVF, KB, VB);
  k_vt<<<dim3(8,2,8), dim3(256), 0, stream>>>(VB, VT);
  k_attnM<<<dim3(48,16), dim3(256), 0, stream>>>(QB, KB, VT, MB, ws+OFF_ATTN);
  k_out<<<dim3(48,2), dim3(256), 0, stream>>>(ws+OFF_ATTN, ws+OFF_WO, ws+OFF_BO, out);
}